// Round 4
// baseline (177.659 us; speedup 1.0000x reference)
//
#include <hip/hip_runtime.h>
#include <hip/hip_bf16.h>

// LFQ forward fused kernels for MI355X (gfx950).
// Outputs in d_out (float32): out[16384*512], indices[16384] (as float), aux_loss[1]
// ws layout: P[512][4096] partials (8 MB) | scal {C_sum, E_sum, done_count}

#define NS    16384      // samples = 4*4096
#define NOUT  (NS*512)   // 8388608
#define AUXO  (NOUT+NS)  // 8404992
#define INVT2 200.0f     // 2 * inv_temperature
#define NBLK  512        // K1 blocks; 32 samples each

// -------- K1: xp, indices, out-projection, factorized softmax entropy + avg_prob partials
// One sample per 16-lane group; 4 samples/wave; 8 waves/block; 512 blocks (2 blocks/CU).
// Weights are read DIRECTLY from global (L1/L2-resident, static addresses) instead of
// LDS staging: moves ~192 wide reads/wave off the serialized per-CU DS pipe onto the
// VMEM pipe, and removes the staging barrier. Values and FMA order are identical to
// the LDS version -> xp / indices / out bitwise identical.
__global__ __launch_bounds__(512, 4) void k_main(
    const float* __restrict__ x,
    const float* __restrict__ w_in,  const float* __restrict__ b_in,
    const float* __restrict__ w_out, const float* __restrict__ b_out,
    float* __restrict__ out, float* __restrict__ idx_out,
    float* __restrict__ P, float* __restrict__ Csum) {

  __shared__ float s_phi[32][64];   // per-sample high-6-bit softmax probs
  __shared__ float s_psi[32][64];   // per-sample low-6-bit softmax probs
  __shared__ float s_xp[8][4][12];  // per-wave xp broadcast
  __shared__ float s_h[8];

  const int t = threadIdx.x;
  const int wave = t >> 6, lane = t & 63;
  const int g = lane >> 4, sub = lane & 15;

  const float4* wi4 = (const float4*)w_in;    // [12][128] float4 view of w_in[12][512]
  const float4* wo4 = (const float4*)w_out;   // [512*3]   float4 view of w_out[512][12]
  const float4* bo4 = (const float4*)b_out;

  float bin[12];
  #pragma unroll
  for (int d = 0; d < 12; ++d) bin[d] = b_in[d];

  // ---- one sample per lane-group
  const int i0 = blockIdx.x * 32 + wave * 4 + g;

  const float4* xr0 = (const float4*)(x + (size_t)i0 * 512 + sub * 32);
  float4 xv0[8];
  #pragma unroll
  for (int e4 = 0; e4 < 8; ++e4) xv0[e4] = xr0[e4];

  // ---- partial dots for 12 dims.
  // Old: s_wi float4 [d*128 + e4*16 + sub] held w_in[d*512 + sub*32 + e4*4 + {0..3}].
  // New: raw w_in float4 [d*128 + sub*8 + e4] is the SAME 4 floats -> bitwise equal.
  float p0[12];
  #pragma unroll
  for (int d = 0; d < 12; ++d) p0[d] = 0.f;
  #pragma unroll
  for (int e4 = 0; e4 < 8; ++e4) {
    #pragma unroll
    for (int d = 0; d < 12; ++d) {
      float4 w4 = wi4[d * 128 + sub * 8 + e4];
      p0[d] += xv0[e4].x * w4.x + xv0[e4].y * w4.y + xv0[e4].z * w4.z + xv0[e4].w * w4.w;
    }
  }
  // ---- reduce across the 16 lanes of the sample (same tree -> bitwise equal)
  #pragma unroll
  for (int d = 0; d < 12; ++d) {
    #pragma unroll
    for (int m = 1; m <= 8; m <<= 1) {
      p0[d] += __shfl_xor(p0[d], m, 16);
    }
    p0[d] += bin[d];
  }

  // ---- indices (bit 11-d set iff xp_d > 0)
  unsigned idx0 = 0u;
  #pragma unroll
  for (int d = 0; d < 12; ++d) {
    idx0 |= (p0[d] > 0.f ? 1u : 0u) << (11 - d);
  }
  if (sub == 0) {
    idx_out[i0] = (float)idx0;
    #pragma unroll
    for (int d = 0; d < 12; ++d) s_xp[wave][g][d] = p0[d];
  }

  // ---- out row: out[e] = b_out[e] + sum_d sign(xp_d) * w_out[e][d]
  // Old: s_wt float4 [d*128+M] = (w_out[4M][d], w_out[4M+1][d], w_out[4M+2][d], w_out[4M+3][d]),
  //      accumulated o.{x,y,z,w} += sg[d]*... over ascending d.
  // New: read w_out rows 4M..4M+3 directly (12 contiguous float4 at wo4[12M]) and
  //      accumulate each output component over ascending d in the same order -> bitwise equal.
  float sg0[12];
  #pragma unroll
  for (int d = 0; d < 12; ++d) sg0[d] = p0[d] > 0.f ? 1.f : -1.f;

  float4* or0 = (float4*)(out + (size_t)i0 * 512);
  #pragma unroll
  for (int e4 = 0; e4 < 8; ++e4) {
    const int M = e4 * 16 + sub;
    const float4* wr = wo4 + 12 * M;
    float4 o = bo4[M];
    {   // row 4M -> o.x
      float4 a = wr[0], b = wr[1], c = wr[2];
      o.x += sg0[0]*a.x; o.x += sg0[1]*a.y; o.x += sg0[2]*a.z; o.x += sg0[3]*a.w;
      o.x += sg0[4]*b.x; o.x += sg0[5]*b.y; o.x += sg0[6]*b.z; o.x += sg0[7]*b.w;
      o.x += sg0[8]*c.x; o.x += sg0[9]*c.y; o.x += sg0[10]*c.z; o.x += sg0[11]*c.w;
    }
    {   // row 4M+1 -> o.y
      float4 a = wr[3], b = wr[4], c = wr[5];
      o.y += sg0[0]*a.x; o.y += sg0[1]*a.y; o.y += sg0[2]*a.z; o.y += sg0[3]*a.w;
      o.y += sg0[4]*b.x; o.y += sg0[5]*b.y; o.y += sg0[6]*b.z; o.y += sg0[7]*b.w;
      o.y += sg0[8]*c.x; o.y += sg0[9]*c.y; o.y += sg0[10]*c.z; o.y += sg0[11]*c.w;
    }
    {   // row 4M+2 -> o.z
      float4 a = wr[6], b = wr[7], c = wr[8];
      o.z += sg0[0]*a.x; o.z += sg0[1]*a.y; o.z += sg0[2]*a.z; o.z += sg0[3]*a.w;
      o.z += sg0[4]*b.x; o.z += sg0[5]*b.y; o.z += sg0[6]*b.z; o.z += sg0[7]*b.w;
      o.z += sg0[8]*c.x; o.z += sg0[9]*c.y; o.z += sg0[10]*c.z; o.z += sg0[11]*c.w;
    }
    {   // row 4M+3 -> o.w
      float4 a = wr[9], b = wr[10], c = wr[11];
      o.w += sg0[0]*a.x; o.w += sg0[1]*a.y; o.w += sg0[2]*a.z; o.w += sg0[3]*a.w;
      o.w += sg0[4]*b.x; o.w += sg0[5]*b.y; o.w += sg0[6]*b.z; o.w += sg0[7]*b.w;
      o.w += sg0[8]*c.x; o.w += sg0[9]*c.y; o.w += sg0[10]*c.z; o.w += sg0[11]*c.w;
    }
    or0[M] = o;   // lanes sub=0..15 cover 256 contiguous bytes per instr
  }

  // ---- entropy: all 64 lanes process each of the wave's 4 samples
  float hacc = 0.f;
  #pragma unroll 1
  for (int s = 0; s < 4; ++s) {
    float xq[12];
    #pragma unroll
    for (int d = 0; d < 12; ++d) xq[d] = s_xp[wave][s][d];

    float hi = 0.f, lo = 0.f, ah = 0.f, al = 0.f;
    #pragma unroll
    for (int d = 0; d < 6; ++d) {
      int bh = (lane >> (5 - d)) & 1;
      hi += bh ? xq[d]     : -xq[d];
      lo += bh ? xq[6 + d] : -xq[6 + d];
      ah += fabsf(xq[d]);
      al += fabsf(xq[6 + d]);
    }
    float lhi = INVT2 * (hi - ah);   // <= 0, max over lanes == 0
    float llo = INVT2 * (lo - al);
    float ehi = __expf(lhi);
    float elo = __expf(llo);
    float Shi = ehi, Slo = elo;
    #pragma unroll
    for (int m = 1; m <= 32; m <<= 1) {
      Shi += __shfl_xor(Shi, m);
      Slo += __shfl_xor(Slo, m);
    }
    float phi = ehi / Shi;
    float psi = elo / Slo;
    float lnShi = __logf(Shi), lnSlo = __logf(Slo);
    // factorized per-sample entropy: H = -(sum phi log phi + sum psi log psi)
    hacc += phi * (lhi - lnShi) + psi * (llo - lnSlo);

    const int ws = wave * 4 + s;
    s_phi[ws][lane] = phi;
    s_psi[ws][lane] = psi;
  }

  // ---- per-sample-entropy: wave reduce, then block reduce
  #pragma unroll
  for (int m = 1; m <= 32; m <<= 1) hacc += __shfl_xor(hacc, m);
  if (lane == 0) s_h[wave] = hacc;
  __syncthreads();   // also publishes s_phi/s_psi for phase B
  if (t == 0) {
    float hs = 0.f;
    for (int w2 = 0; w2 < 8; ++w2) hs += s_h[w2];
    atomicAdd(Csum, hs);
  }

  // ---- phase B: avg_prob partial P[j][l] = sum_s phi[s][j]*psi[s][l]
  // each thread owns a 4(j) x 2(l) code tile -> 8 accumulator registers
  const int jb = (t >> 5) * 4;   // 16 j-tiles of 4
  const int lb = (t & 31) * 2;   // 32 l-tiles of 2
  float a00 = 0.f, a01 = 0.f, a10 = 0.f, a11 = 0.f;
  float a20 = 0.f, a21 = 0.f, a30 = 0.f, a31 = 0.f;
  #pragma unroll 4
  for (int s = 0; s < 32; ++s) {
    float4 ph = *(const float4*)&s_phi[s][jb];
    float2 ps = *(const float2*)&s_psi[s][lb];
    a00 += ph.x * ps.x; a01 += ph.x * ps.y;
    a10 += ph.y * ps.x; a11 += ph.y * ps.y;
    a20 += ph.z * ps.x; a21 += ph.z * ps.y;
    a30 += ph.w * ps.x; a31 += ph.w * ps.y;
  }
  float* Pr = P + (size_t)blockIdx.x * 4096;
  *(float2*)&Pr[(jb + 0) * 64 + lb] = make_float2(a00, a01);
  *(float2*)&Pr[(jb + 1) * 64 + lb] = make_float2(a10, a11);
  *(float2*)&Pr[(jb + 2) * 64 + lb] = make_float2(a20, a21);
  *(float2*)&Pr[(jb + 3) * 64 + lb] = make_float2(a30, a31);
}

// -------- K2: reduce partials -> avg_prob, codebook entropy; last block emits aux_loss
__global__ __launch_bounds__(256) void k_reduce(const float* __restrict__ P,
                                                float* __restrict__ scal,
                                                float* __restrict__ aux) {
  __shared__ float red[16][17];
  __shared__ float ered[16];
  const int t = threadIdx.x;
  const int cl = t & 15, rg = t >> 4;
  const int c = blockIdx.x * 16 + cl;
  float s = 0.f;
  #pragma unroll
  for (int k = 0; k < 32; ++k) s += P[(size_t)(rg + k * 16) * 4096 + c];
  red[rg][cl] = s;
  __syncthreads();
  if (t < 16) {
    float tot = 0.f;
    #pragma unroll
    for (int r = 0; r < 16; ++r) tot += red[r][t];
    float pb = tot * (1.f / (float)NS);
    ered[t] = pb * __logf(fmaxf(pb, 1e-5f));   // p * log(clip(p, eps))
  }
  __syncthreads();
  if (t == 0) {
    float e = 0.f;
    #pragma unroll
    for (int r = 0; r < 16; ++r) e += ered[r];
    atomicAdd(&scal[1], e);
    __threadfence();
    unsigned done = atomicAdd((unsigned*)&scal[2], 1u);
    if (done == 255u) {   // last of 256 blocks: final combine (folded k_final)
      float E = atomicAdd(&scal[1], 0.f);   // coherent reads via atomic
      float C = atomicAdd(&scal[0], 0.f);
      float per_sample_entropy = -C * (1.f / (float)NS);
      float codebook_entropy   = -E;
      aux[0] = 0.1f * (per_sample_entropy - codebook_entropy);
    }
  }
}

extern "C" void kernel_launch(void* const* d_in, const int* in_sizes, int n_in,
                              void* d_out, int out_size, void* d_ws, size_t ws_size,
                              hipStream_t stream) {
  const float* x     = (const float*)d_in[0];
  const float* w_in  = (const float*)d_in[1];
  const float* b_in  = (const float*)d_in[2];
  const float* w_out = (const float*)d_in[3];
  const float* b_out = (const float*)d_in[4];
  float* out = (float*)d_out;

  float* P    = (float*)d_ws;                                   // 512*4096 f32 = 8 MB
  float* scal = P + (size_t)NBLK * 4096;                        // {C_sum, E_sum, done}

  hipMemsetAsync(scal, 0, 3 * sizeof(float), stream);
  k_main<<<NBLK, 512, 0, stream>>>(x, w_in, b_in, w_out, b_out,
                                   out, out + NOUT, P, scal);
  k_reduce<<<256, 256, 0, stream>>>(P, scal, out + AUXO);
}

// Round 5
// 118.946 us; speedup vs baseline: 1.4936x; 1.4936x over previous
//
#include <hip/hip_runtime.h>
#include <hip/hip_bf16.h>

// LFQ forward fused kernels for MI355X (gfx950).
// Outputs in d_out (float32): out[16384*512], indices[16384] (as float), aux_loss[1]
// ws layout: T[4096][512] out-row table (8 MB) | P[512][4096] partials (8 MB)
//            | scal {C_sum, E_sum, done_count}

#define NS    16384      // samples = 4*4096
#define NOUT  (NS*512)   // 8388608
#define AUXO  (NOUT+NS)  // 8404992
#define INVT2 200.0f     // 2 * inv_temperature
#define NBLK  512        // K1 blocks; 32 samples each
#define RBLK  64         // K2 blocks

// DPP-based butterfly add step, bitwise-equal to  v += __shfl_xor(v, m)  for
// m=1 (0xB1 quad_perm[1,0,3,2]), m=2 (0x4E quad_perm[2,3,0,1]),
// m=4 (0x141 half_mirror; equal because quads are uniform after steps 1,2),
// m=8 (0x140 mirror; equal because 8-groups are uniform after step 4).
// Runs on the VALU pipe instead of the DS pipe.
template <int CTRL>
__device__ inline float dpp_add(float v) {
  int p = __builtin_amdgcn_update_dpp(0, __float_as_int(v), CTRL, 0xF, 0xF, true);
  return v + __int_as_float(p);
}
__device__ inline float rdlane(float v, int lane) {
  return __int_as_float(__builtin_amdgcn_readlane(__float_as_int(v), lane));
}

// -------- K0: precompute all 4096 possible output rows (verified bitwise in R3).
// T[c][e] = b_out[e] + sum_d sg_d(c) * w_out[e][d], sg_d = +1 iff bit (11-d) of c set.
__global__ __launch_bounds__(512) void k_table(const float* __restrict__ w_out,
                                               const float* __restrict__ b_out,
                                               float* __restrict__ T) {
  __shared__ float s_wt[6144];   // f = d*512 + e holds w_out[e][d]
  const int t = threadIdx.x;
  #pragma unroll
  for (int k = 0; k < 12; ++k) s_wt[t + k * 512] = w_out[t * 12 + k];
  __syncthreads();

  const int c = blockIdx.x * 16 + (t >> 5);   // 16 codes per block, 4096 total
  float sg[12];
  #pragma unroll
  for (int d = 0; d < 12; ++d) sg[d] = ((c >> (11 - d)) & 1) ? 1.f : -1.f;

  float4* Trow = (float4*)(T + (size_t)c * 512);
  #pragma unroll
  for (int k4 = 0; k4 < 4; ++k4) {
    const int m = (t & 31) + k4 * 32;         // float4 index within the 512-row
    float4 bo = ((const float4*)b_out)[m];
    float4 o = bo;
    #pragma unroll
    for (int d = 0; d < 12; ++d) {
      float4 w4 = ((const float4*)s_wt)[d * 128 + m];
      o.x += sg[d] * w4.x; o.y += sg[d] * w4.y; o.z += sg[d] * w4.z; o.w += sg[d] * w4.w;
    }
    Trow[m] = o;
  }
}

// -------- K1: xp, indices, out-row gather, factorized softmax entropy + avg_prob partials
// One sample per 16-lane group; 4/wave; 8 waves/block; 512 blocks (16 waves/CU).
// Dot partition / tree bitwise-identical to prior passing rounds. Out = T-gather
// (bitwise, R3-verified). Entropy cross-lane moved to DPP/readlane (bitwise — see above).
__global__ __launch_bounds__(512, 4) void k_main(
    const float* __restrict__ x,
    const float* __restrict__ w_in,  const float* __restrict__ b_in,
    const float* __restrict__ T,
    float* __restrict__ out, float* __restrict__ idx_out,
    float* __restrict__ P, float* __restrict__ Csum) {

  __shared__ float s_wi[6144];      // w_in swizzled: [d][e4][sub] float4s (dot partition)
  __shared__ float s_phi[32][64];   // per-sample high-6-bit softmax probs
  __shared__ float s_psi[32][64];   // per-sample low-6-bit softmax probs
  __shared__ float s_h[8];

  const int t = threadIdx.x;

  // stage w_in: element (d, e) with e = sub*32 + e4*4 + kk stored at
  //   f = ((d*128 + e4*16 + sub)*4 + kk) -> lane-sub b128 reads conflict-free.
  #pragma unroll
  for (int k = 0; k < 12; ++k) {
    int f  = t + k * 512;
    int kk = f & 3;
    int q  = f >> 2;
    int sub = q & 15, e4 = (q >> 4) & 7, d = q >> 7;
    int e  = sub * 32 + e4 * 4 + kk;
    s_wi[f] = w_in[d * 512 + e];
  }
  __syncthreads();

  const int wave = t >> 6, lane = t & 63;
  const int g = lane >> 4, sub = lane & 15;

  float bin[12];
  #pragma unroll
  for (int d = 0; d < 12; ++d) bin[d] = b_in[d];

  // ---- one sample per lane-group
  const int i0 = blockIdx.x * 32 + wave * 4 + g;

  const float4* xr0 = (const float4*)(x + (size_t)i0 * 512 + sub * 32);
  float4 xv0[8];
  #pragma unroll
  for (int e4 = 0; e4 < 8; ++e4) xv0[e4] = xr0[e4];

  // ---- partial dots for 12 dims (unchanged, bitwise)
  float p0[12];
  #pragma unroll
  for (int d = 0; d < 12; ++d) p0[d] = 0.f;
  #pragma unroll
  for (int e4 = 0; e4 < 8; ++e4) {
    #pragma unroll
    for (int d = 0; d < 12; ++d) {
      float4 w4 = ((const float4*)s_wi)[d * 128 + e4 * 16 + sub];
      p0[d] += xv0[e4].x * w4.x + xv0[e4].y * w4.y + xv0[e4].z * w4.z + xv0[e4].w * w4.w;
    }
  }
  // ---- reduce across the 16 lanes of the sample (same tree -> bitwise equal)
  #pragma unroll
  for (int d = 0; d < 12; ++d) {
    #pragma unroll
    for (int m = 1; m <= 8; m <<= 1) {
      p0[d] += __shfl_xor(p0[d], m, 16);
    }
    p0[d] += bin[d];
  }

  // ---- indices (bit 11-d set iff xp_d > 0)
  unsigned idx0 = 0u;
  #pragma unroll
  for (int d = 0; d < 12; ++d) {
    idx0 |= (p0[d] > 0.f ? 1u : 0u) << (11 - d);
  }
  if (sub == 0) {
    idx_out[i0] = (float)idx0;
  }

  // ---- out row: gather precomputed row T[idx0] (bitwise = FMA path; R3-verified).
  {
    const float4* Trow = (const float4*)(T + (size_t)idx0 * 512);
    float4* or0 = (float4*)(out + (size_t)i0 * 512);
    #pragma unroll
    for (int e4 = 0; e4 < 8; ++e4) {
      or0[e4 * 16 + sub] = Trow[e4 * 16 + sub];
    }
  }

  // ---- entropy: all 64 lanes process each of the wave's 4 samples.
  // xp broadcast via readlane (same bits as the old s_xp LDS path); softmax sum via
  // DPP butterfly (steps 1,2,4,8 bitwise-equal) + readlane pairs grouped
  // (r0+r1)+(r2+r3) to match the old step-16/32 result bitwise.
  float hacc = 0.f;
  #pragma unroll
  for (int s = 0; s < 4; ++s) {
    float xq[12];
    #pragma unroll
    for (int d = 0; d < 12; ++d) xq[d] = rdlane(p0[d], 16 * s);

    float hi = 0.f, lo = 0.f, ah = 0.f, al = 0.f;
    #pragma unroll
    for (int d = 0; d < 6; ++d) {
      int bh = (lane >> (5 - d)) & 1;
      hi += bh ? xq[d]     : -xq[d];
      lo += bh ? xq[6 + d] : -xq[6 + d];
      ah += fabsf(xq[d]);
      al += fabsf(xq[6 + d]);
    }
    float lhi = INVT2 * (hi - ah);   // <= 0, max over lanes == 0
    float llo = INVT2 * (lo - al);
    float ehi = __expf(lhi);
    float elo = __expf(llo);

    float Shi = ehi, Slo = elo;
    Shi = dpp_add<0xB1>(Shi);  Slo = dpp_add<0xB1>(Slo);   // xor 1
    Shi = dpp_add<0x4E>(Shi);  Slo = dpp_add<0x4E>(Slo);   // xor 2
    Shi = dpp_add<0x141>(Shi); Slo = dpp_add<0x141>(Slo);  // xor 4 (half_mirror)
    Shi = dpp_add<0x140>(Shi); Slo = dpp_add<0x140>(Slo);  // xor 8 (mirror)
    {
      float r0 = rdlane(Shi, 0), r1 = rdlane(Shi, 16), r2 = rdlane(Shi, 32), r3 = rdlane(Shi, 48);
      Shi = (r0 + r1) + (r2 + r3);
      float q0 = rdlane(Slo, 0), q1 = rdlane(Slo, 16), q2 = rdlane(Slo, 32), q3 = rdlane(Slo, 48);
      Slo = (q0 + q1) + (q2 + q3);
    }

    float phi = ehi / Shi;
    float psi = elo / Slo;
    float lnShi = __logf(Shi), lnSlo = __logf(Slo);
    // factorized per-sample entropy: H = -(sum phi log phi + sum psi log psi)
    hacc += phi * (lhi - lnShi) + psi * (llo - lnSlo);

    const int ws = wave * 4 + s;
    s_phi[ws][lane] = phi;
    s_psi[ws][lane] = psi;
  }

  // ---- per-sample-entropy: wave reduce, then block reduce
  #pragma unroll
  for (int m = 1; m <= 32; m <<= 1) hacc += __shfl_xor(hacc, m);
  if (lane == 0) s_h[wave] = hacc;
  __syncthreads();   // also publishes s_phi/s_psi for phase B
  if (t == 0) {
    float hs = 0.f;
    for (int w2 = 0; w2 < 8; ++w2) hs += s_h[w2];
    atomicAdd(Csum, hs);
  }

  // ---- phase B: avg_prob partial P[j][l] = sum_s phi[s][j]*psi[s][l]
  // each thread owns a 4(j) x 2(l) code tile -> 8 accumulator registers
  const int jb = (t >> 5) * 4;   // 16 j-tiles of 4
  const int lb = (t & 31) * 2;   // 32 l-tiles of 2
  float a00 = 0.f, a01 = 0.f, a10 = 0.f, a11 = 0.f;
  float a20 = 0.f, a21 = 0.f, a30 = 0.f, a31 = 0.f;
  #pragma unroll 4
  for (int s = 0; s < 32; ++s) {
    float4 ph = *(const float4*)&s_phi[s][jb];
    float2 ps = *(const float2*)&s_psi[s][lb];
    a00 += ph.x * ps.x; a01 += ph.x * ps.y;
    a10 += ph.y * ps.x; a11 += ph.y * ps.y;
    a20 += ph.z * ps.x; a21 += ph.z * ps.y;
    a30 += ph.w * ps.x; a31 += ph.w * ps.y;
  }
  float* Pr = P + (size_t)blockIdx.x * 4096;
  *(float2*)&Pr[(jb + 0) * 64 + lb] = make_float2(a00, a01);
  *(float2*)&Pr[(jb + 1) * 64 + lb] = make_float2(a10, a11);
  *(float2*)&Pr[(jb + 2) * 64 + lb] = make_float2(a20, a21);
  *(float2*)&Pr[(jb + 3) * 64 + lb] = make_float2(a30, a31);
}

// -------- K2: reduce partials -> avg_prob, codebook entropy; last block emits aux_loss.
// Coalesced: wave reads 64 consecutive columns (256 B/instruction); 64 blocks x 4 waves.
__global__ __launch_bounds__(256) void k_reduce(const float* __restrict__ P,
                                                float* __restrict__ scal,
                                                float* __restrict__ aux) {
  __shared__ float red[4][64];
  const int t = threadIdx.x;
  const int c = blockIdx.x * 64 + (t & 63);
  const int rg = t >> 6;                       // 4 row-groups of 128 rows
  float s = 0.f;
  #pragma unroll 8
  for (int j = 0; j < 128; ++j) s += P[(size_t)(rg * 128 + j) * 4096 + c];
  red[rg][t & 63] = s;
  __syncthreads();
  if (t < 64) {
    float tot = (red[0][t] + red[1][t]) + (red[2][t] + red[3][t]);
    float pb = tot * (1.f / (float)NS);
    float e = pb * __logf(fmaxf(pb, 1e-5f));   // p * log(clip(p, eps))
    #pragma unroll
    for (int m = 1; m <= 32; m <<= 1) e += __shfl_xor(e, m);
    if (t == 0) {
      atomicAdd(&scal[1], e);
      __threadfence();
      unsigned done = atomicAdd((unsigned*)&scal[2], 1u);
      if (done == RBLK - 1) {   // last block: final combine (folded k_final)
        float E = atomicAdd(&scal[1], 0.f);   // coherent reads via atomic
        float C = atomicAdd(&scal[0], 0.f);
        float per_sample_entropy = -C * (1.f / (float)NS);
        float codebook_entropy   = -E;
        aux[0] = 0.1f * (per_sample_entropy - codebook_entropy);
      }
    }
  }
}

extern "C" void kernel_launch(void* const* d_in, const int* in_sizes, int n_in,
                              void* d_out, int out_size, void* d_ws, size_t ws_size,
                              hipStream_t stream) {
  const float* x     = (const float*)d_in[0];
  const float* w_in  = (const float*)d_in[1];
  const float* b_in  = (const float*)d_in[2];
  const float* w_out = (const float*)d_in[3];
  const float* b_out = (const float*)d_in[4];
  float* out = (float*)d_out;

  float* T    = (float*)d_ws;                                   // 4096*512 f32 = 8 MB
  float* P    = T + (size_t)4096 * 512;                         // 512*4096 f32 = 8 MB
  float* scal = P + (size_t)NBLK * 4096;                        // {C_sum, E_sum, done}

  hipMemsetAsync(scal, 0, 3 * sizeof(float), stream);
  k_table<<<256, 512, 0, stream>>>(w_out, b_out, T);
  k_main<<<NBLK, 512, 0, stream>>>(x, w_in, b_in, T,
                                   out, out + NOUT, P, scal);
  k_reduce<<<RBLK, 256, 0, stream>>>(P, scal, out + AUXO);
}

// Round 6
// 116.097 us; speedup vs baseline: 1.5303x; 1.0245x over previous
//
#include <hip/hip_runtime.h>
#include <hip/hip_bf16.h>

// LFQ forward fused kernels for MI355X (gfx950).
// Outputs in d_out (float32): out[16384*512], indices[16384] (as float), aux_loss[1]
// ws layout: P[256][4096] partials (4 MB) | xp[16384][12] (786 KB)
//            | scal {C_sum, E_sum, done_count}

#define NS    16384      // samples = 4*4096
#define NOUT  (NS*512)   // 8388608
#define AUXO  (NOUT+NS)  // 8404992
#define INVT2 200.0f     // 2 * inv_temperature
#define PBLK  256        // k_proj blocks; 64 samples each
#define EBLK  256        // k_ent blocks; 64 samples each
#define RBLK  64         // k_reduce blocks

// DPP-based butterfly add step, bitwise-equal to  v += __shfl_xor(v, m)  for
// m=1 (0xB1 quad_perm[1,0,3,2]), m=2 (0x4E quad_perm[2,3,0,1]),
// m=4 (0x141 half_mirror; equal because quads are uniform after steps 1,2),
// m=8 (0x140 mirror; equal because 8-groups are uniform after step 4).
template <int CTRL>
__device__ inline float dpp_add(float v) {
  int p = __builtin_amdgcn_update_dpp(0, __float_as_int(v), CTRL, 0xF, 0xF, true);
  return v + __int_as_float(p);
}
__device__ inline float rdlane(float v, int lane) {
  return __int_as_float(__builtin_amdgcn_readlane(__float_as_int(v), lane));
}

// -------- K1: streaming projection — xp, indices, out. (R1 body, bitwise-proven;
// entropy/phase-B removed so there are no post-staging barriers.)
// Two samples per lane (weight reads amortized); 8 samples/wave; 64/block; 256 blocks.
__global__ __launch_bounds__(512, 2) void k_proj(
    const float* __restrict__ x,
    const float* __restrict__ w_in,  const float* __restrict__ b_in,
    const float* __restrict__ w_out, const float* __restrict__ b_out,
    float* __restrict__ out, float* __restrict__ idx_out,
    float* __restrict__ xp_out) {

  __shared__ float s_wi[6144];      // w_in swizzled: [d][e4][sub] float4s (dot partition)
  __shared__ float s_wt[6144];      // w_out^T swizzled for coalesced store partition

  const int t = threadIdx.x;

  // s_wi: element (d, e) with e = sub*32 + e4*4 + kk stored at f = ((d*128+e4*16+sub)*4+kk).
  // s_wt: float f = d*512 + e holds w_out[e][d]  -> out-proj reads give coalesced stores.
  for (int k = 0; k < 12; ++k) {
    int f  = t + k * 512;
    int kk = f & 3;
    int q  = f >> 2;
    int sub = q & 15, e4 = (q >> 4) & 7, d = q >> 7;
    int e  = sub * 32 + e4 * 4 + kk;
    s_wi[f] = w_in[d * 512 + e];
    s_wt[f] = w_out[t * 12 + k];   // f = t + k*512 -> e = t, d = k
  }
  __syncthreads();

  const int wave = t >> 6, lane = t & 63;
  const int g = lane >> 4, sub = lane & 15;

  float bin[12];
  #pragma unroll
  for (int d = 0; d < 12; ++d) bin[d] = b_in[d];

  // ---- two samples per lane
  const int i0 = blockIdx.x * 64 + wave * 8 + g;
  const int i1 = i0 + 4;

  const float4* xr0 = (const float4*)(x + (size_t)i0 * 512 + sub * 32);
  const float4* xr1 = (const float4*)(x + (size_t)i1 * 512 + sub * 32);
  float4 xv0[8], xv1[8];
  #pragma unroll
  for (int e4 = 0; e4 < 8; ++e4) { xv0[e4] = xr0[e4]; xv1[e4] = xr1[e4]; }

  // ---- partial dots for 12 dims, both samples per weight read
  float p0[12], p1[12];
  #pragma unroll
  for (int d = 0; d < 12; ++d) { p0[d] = 0.f; p1[d] = 0.f; }
  #pragma unroll
  for (int e4 = 0; e4 < 8; ++e4) {
    #pragma unroll
    for (int d = 0; d < 12; ++d) {
      float4 w4 = ((const float4*)s_wi)[d * 128 + e4 * 16 + sub];
      p0[d] += xv0[e4].x * w4.x + xv0[e4].y * w4.y + xv0[e4].z * w4.z + xv0[e4].w * w4.w;
      p1[d] += xv1[e4].x * w4.x + xv1[e4].y * w4.y + xv1[e4].z * w4.z + xv1[e4].w * w4.w;
    }
  }
  // ---- reduce across the 16 lanes of each sample (same tree -> bitwise equal)
  #pragma unroll
  for (int d = 0; d < 12; ++d) {
    #pragma unroll
    for (int m = 1; m <= 8; m <<= 1) {
      p0[d] += __shfl_xor(p0[d], m, 16);
      p1[d] += __shfl_xor(p1[d], m, 16);
    }
    p0[d] += bin[d];
    p1[d] += bin[d];
  }

  // ---- indices
  unsigned idx0 = 0u, idx1 = 0u;
  #pragma unroll
  for (int d = 0; d < 12; ++d) {
    idx0 |= (p0[d] > 0.f ? 1u : 0u) << (11 - d);
    idx1 |= (p1[d] > 0.f ? 1u : 0u) << (11 - d);
  }
  if (sub == 0) {
    idx_out[i0] = (float)idx0;
    idx_out[i1] = (float)idx1;
  }

  // ---- spill xp for k_ent: all 16 lanes hold the full p vector after the tree;
  // lanes sub=0..2 each write one float4 (static component indices -> no scratch).
  {
    float4 v0 = make_float4(p0[0], p0[1], p0[2], p0[3]);
    float4 v1 = make_float4(p1[0], p1[1], p1[2], p1[3]);
    if (sub == 1) { v0 = make_float4(p0[4], p0[5], p0[6], p0[7]);
                    v1 = make_float4(p1[4], p1[5], p1[6], p1[7]); }
    if (sub == 2) { v0 = make_float4(p0[8], p0[9], p0[10], p0[11]);
                    v1 = make_float4(p1[8], p1[9], p1[10], p1[11]); }
    if (sub < 3) {
      ((float4*)(xp_out + (size_t)i0 * 12))[sub] = v0;
      ((float4*)(xp_out + (size_t)i1 * 12))[sub] = v1;
    }
  }

  // ---- out rows: out[e] = b_out[e] + sum_d sign(xp_d) * w_out[e][d]  (coalesced)
  float sg0[12], sg1[12];
  #pragma unroll
  for (int d = 0; d < 12; ++d) {
    sg0[d] = p0[d] > 0.f ? 1.f : -1.f;
    sg1[d] = p1[d] > 0.f ? 1.f : -1.f;
  }
  float4* or0 = (float4*)(out + (size_t)i0 * 512);
  float4* or1 = (float4*)(out + (size_t)i1 * 512);
  #pragma unroll
  for (int e4 = 0; e4 < 8; ++e4) {
    float4 bo = ((const float4*)b_out)[e4 * 16 + sub];
    float4 o0 = bo, o1 = bo;
    #pragma unroll
    for (int d = 0; d < 12; ++d) {
      float4 w4 = ((const float4*)s_wt)[d * 128 + e4 * 16 + sub];
      o0.x += sg0[d] * w4.x; o0.y += sg0[d] * w4.y; o0.z += sg0[d] * w4.z; o0.w += sg0[d] * w4.w;
      o1.x += sg1[d] * w4.x; o1.y += sg1[d] * w4.y; o1.z += sg1[d] * w4.z; o1.w += sg1[d] * w4.w;
    }
    or0[e4 * 16 + sub] = o0;
    or1[e4 * 16 + sub] = o1;
  }
}

// -------- K2: entropy + avg_prob partials from xp (786 KB, L2-resident).
// 64 samples/block; per-sample math identical (bitwise) to the R5 DPP path.
__global__ __launch_bounds__(512) void k_ent(
    const float* __restrict__ xp,
    float* __restrict__ P, float* __restrict__ scal) {

  __shared__ float s_phi[64][64];   // per-sample high-6-bit softmax probs
  __shared__ float s_psi[64][64];   // per-sample low-6-bit softmax probs
  __shared__ float s_h[8];

  const int t = threadIdx.x;
  const int wave = t >> 6, lane = t & 63;
  const int sbase = blockIdx.x * 64 + wave * 8;

  float hacc = 0.f;
  #pragma unroll 1
  for (int s = 0; s < 8; ++s) {
    // wave-uniform sample base -> scalar loads
    const float* xps = xp + (size_t)(sbase + s) * 12;
    float xq[12];
    #pragma unroll
    for (int d = 0; d < 12; ++d) xq[d] = xps[d];

    float hi = 0.f, lo = 0.f, ah = 0.f, al = 0.f;
    #pragma unroll
    for (int d = 0; d < 6; ++d) {
      int bh = (lane >> (5 - d)) & 1;
      hi += bh ? xq[d]     : -xq[d];
      lo += bh ? xq[6 + d] : -xq[6 + d];
      ah += fabsf(xq[d]);
      al += fabsf(xq[6 + d]);
    }
    float lhi = INVT2 * (hi - ah);   // <= 0, max over lanes == 0
    float llo = INVT2 * (lo - al);
    float ehi = __expf(lhi);
    float elo = __expf(llo);

    float Shi = ehi, Slo = elo;
    Shi = dpp_add<0xB1>(Shi);  Slo = dpp_add<0xB1>(Slo);   // xor 1
    Shi = dpp_add<0x4E>(Shi);  Slo = dpp_add<0x4E>(Slo);   // xor 2
    Shi = dpp_add<0x141>(Shi); Slo = dpp_add<0x141>(Slo);  // xor 4 (half_mirror)
    Shi = dpp_add<0x140>(Shi); Slo = dpp_add<0x140>(Slo);  // xor 8 (mirror)
    {
      float r0 = rdlane(Shi, 0), r1 = rdlane(Shi, 16), r2 = rdlane(Shi, 32), r3 = rdlane(Shi, 48);
      Shi = (r0 + r1) + (r2 + r3);
      float q0 = rdlane(Slo, 0), q1 = rdlane(Slo, 16), q2 = rdlane(Slo, 32), q3 = rdlane(Slo, 48);
      Slo = (q0 + q1) + (q2 + q3);
    }

    float phi = ehi / Shi;
    float psi = elo / Slo;
    float lnShi = __logf(Shi), lnSlo = __logf(Slo);
    hacc += phi * (lhi - lnShi) + psi * (llo - lnSlo);

    s_phi[wave * 8 + s][lane] = phi;
    s_psi[wave * 8 + s][lane] = psi;
  }

  // ---- per-sample-entropy: wave reduce, then block reduce
  #pragma unroll
  for (int m = 1; m <= 32; m <<= 1) hacc += __shfl_xor(hacc, m);
  if (lane == 0) s_h[wave] = hacc;
  __syncthreads();   // also publishes s_phi/s_psi for phase B
  if (t == 0) {
    float hs = 0.f;
    for (int w2 = 0; w2 < 8; ++w2) hs += s_h[w2];
    atomicAdd(&scal[0], hs);
  }

  // ---- phase B: avg_prob partial P[j][l] = sum_s phi[s][j]*psi[s][l]
  const int jb = (t >> 5) * 4;   // 16 j-tiles of 4
  const int lb = (t & 31) * 2;   // 32 l-tiles of 2
  float a00 = 0.f, a01 = 0.f, a10 = 0.f, a11 = 0.f;
  float a20 = 0.f, a21 = 0.f, a30 = 0.f, a31 = 0.f;
  #pragma unroll 4
  for (int s = 0; s < 64; ++s) {
    float4 ph = *(const float4*)&s_phi[s][jb];
    float2 ps = *(const float2*)&s_psi[s][lb];
    a00 += ph.x * ps.x; a01 += ph.x * ps.y;
    a10 += ph.y * ps.x; a11 += ph.y * ps.y;
    a20 += ph.z * ps.x; a21 += ph.z * ps.y;
    a30 += ph.w * ps.x; a31 += ph.w * ps.y;
  }
  float* Pr = P + (size_t)blockIdx.x * 4096;
  *(float2*)&Pr[(jb + 0) * 64 + lb] = make_float2(a00, a01);
  *(float2*)&Pr[(jb + 1) * 64 + lb] = make_float2(a10, a11);
  *(float2*)&Pr[(jb + 2) * 64 + lb] = make_float2(a20, a21);
  *(float2*)&Pr[(jb + 3) * 64 + lb] = make_float2(a30, a31);
}

// -------- K3: reduce partials -> avg_prob, codebook entropy; last block emits aux_loss.
// Coalesced: wave reads 64 consecutive columns (256 B/instruction).
__global__ __launch_bounds__(256) void k_reduce(const float* __restrict__ P,
                                                float* __restrict__ scal,
                                                float* __restrict__ aux) {
  __shared__ float red[4][64];
  const int t = threadIdx.x;
  const int c = blockIdx.x * 64 + (t & 63);
  const int rg = t >> 6;                       // 4 row-groups of 64 rows
  float s = 0.f;
  #pragma unroll 8
  for (int j = 0; j < 64; ++j) s += P[(size_t)(rg * 64 + j) * 4096 + c];
  red[rg][t & 63] = s;
  __syncthreads();
  if (t < 64) {
    float tot = (red[0][t] + red[1][t]) + (red[2][t] + red[3][t]);
    float pb = tot * (1.f / (float)NS);
    float e = pb * __logf(fmaxf(pb, 1e-5f));   // p * log(clip(p, eps))
    #pragma unroll
    for (int m = 1; m <= 32; m <<= 1) e += __shfl_xor(e, m);
    if (t == 0) {
      atomicAdd(&scal[1], e);
      __threadfence();
      unsigned done = atomicAdd((unsigned*)&scal[2], 1u);
      if (done == RBLK - 1) {   // last block: final combine
        float E = atomicAdd(&scal[1], 0.f);   // coherent reads via atomic
        float C = atomicAdd(&scal[0], 0.f);
        float per_sample_entropy = -C * (1.f / (float)NS);
        float codebook_entropy   = -E;
        aux[0] = 0.1f * (per_sample_entropy - codebook_entropy);
      }
    }
  }
}

extern "C" void kernel_launch(void* const* d_in, const int* in_sizes, int n_in,
                              void* d_out, int out_size, void* d_ws, size_t ws_size,
                              hipStream_t stream) {
  const float* x     = (const float*)d_in[0];
  const float* w_in  = (const float*)d_in[1];
  const float* b_in  = (const float*)d_in[2];
  const float* w_out = (const float*)d_in[3];
  const float* b_out = (const float*)d_in[4];
  float* out = (float*)d_out;

  float* P    = (float*)d_ws;                                   // 256*4096 f32 = 4 MB
  float* xp   = P + (size_t)EBLK * 4096;                        // 16384*12 f32 = 786 KB
  float* scal = xp + (size_t)NS * 12;                           // {C_sum, E_sum, done}

  hipMemsetAsync(scal, 0, 3 * sizeof(float), stream);
  k_proj<<<PBLK, 512, 0, stream>>>(x, w_in, b_in, w_out, b_out,
                                   out, out + NOUT, xp);
  k_ent<<<EBLK, 512, 0, stream>>>(xp, P, scal);
  k_reduce<<<RBLK, 256, 0, stream>>>(P, scal, out + AUXO);
}